// Round 3
// baseline (198.519 us; speedup 1.0000x reference)
//
#include <hip/hip_runtime.h>
#include <stdint.h>

// CosmosUnpatcher3d: single-level inverse 3D Haar DWT + slice t>=1.
// Input  (fp32): (2, 24, 9, 256, 256) -> 8 bands x 3 channels along axis 1
// Output (fp32): (2, 3, 17, 512, 512)
// out[n,c,to,h,w] = sum_b sign(b; t,h,w) * in[n, 3b+c, t/2, h/2, w/2],
// internal t = to+1; sign = prod over "high" axes of (-1)^(coord&1).
// Net scale c^3*sqrt(8) == 1.0 exactly, so it's a pure +/- 8-way sum.

// Per thread: 8 bands x 4 w-elems (float4 loads, 128 B in), writes 2x2 rows of
// 8 contiguous fp32 (2x float4 stores each). Grid exactly covers input:
// 2*3*9*256*64 threads = 3456 blocks x 256.
__global__ __launch_bounds__(256) void idwt_haar_kernel(
    const float* __restrict__ in,
    float* __restrict__ out)
{
    const uint32_t flat = blockIdx.x * 256u + threadIdx.x;
    const uint32_t wv = flat & 63u;          // 64 vectors of 4 floats per 256-wide row
    uint32_t rest = flat >> 6;
    const uint32_t h = rest & 255u; rest >>= 8;
    const uint32_t t = rest % 9u;  rest /= 9u;
    const uint32_t c = rest % 3u;
    const uint32_t n = rest / 3u;

    // input offset for band 0: ch = n*24 + c ; band stride = 3*9*65536 = 1769472 elems
    const uint32_t in_off = ((n * 24u + c) * 9u + t) * 65536u + h * 256u + wv * 4u;

    float a[8][4];
#pragma unroll
    for (int b = 0; b < 8; ++b) {
        const float4 v = *reinterpret_cast<const float4*>(in + in_off + (uint32_t)b * 1769472u);
        a[b][0] = v.x; a[b][1] = v.y; a[b][2] = v.z; a[b][3] = v.w;
    }

    // W combine: wst[k][pw][j], k = 2*Tbit + Hbit  (band 2k = W-low, 2k+1 = W-high)
    float wst[4][2][4];
#pragma unroll
    for (int k = 0; k < 4; ++k)
#pragma unroll
        for (int j = 0; j < 4; ++j) {
            wst[k][0][j] = a[2 * k][j] + a[2 * k + 1][j];   // even w
            wst[k][1][j] = a[2 * k][j] - a[2 * k + 1][j];   // odd w
        }

    // H combine: hst[tb][ph][pw][j]
    float hst[2][2][2][4];
#pragma unroll
    for (int tb = 0; tb < 2; ++tb)
#pragma unroll
        for (int pw = 0; pw < 2; ++pw)
#pragma unroll
            for (int j = 0; j < 4; ++j) {
                hst[tb][0][pw][j] = wst[2 * tb][pw][j] + wst[2 * tb + 1][pw][j];
                hst[tb][1][pw][j] = wst[2 * tb][pw][j] - wst[2 * tb + 1][pw][j];
            }

    // T combine + store. internal t_int = 2t+pt ; t_out = t_int - 1.
    const uint32_t out_base = (n * 3u + c) * (17u * 262144u) + h * 1024u + wv * 8u;

#pragma unroll
    for (int pt = 0; pt < 2; ++pt) {
        const int t_out = 2 * (int)t - 1 + pt;
        if (t_out < 0) continue;               // uniform per block (t uniform per block)
#pragma unroll
        for (int ph = 0; ph < 2; ++ph) {
            float f[8];
#pragma unroll
            for (int j = 0; j < 4; ++j) {
                float e0 = hst[0][ph][0][j], e1 = hst[1][ph][0][j];
                float o0 = hst[0][ph][1][j], o1 = hst[1][ph][1][j];
                f[2 * j]     = (pt == 0) ? (e0 + e1) : (e0 - e1);   // even w
                f[2 * j + 1] = (pt == 0) ? (o0 + o1) : (o0 - o1);   // odd w
            }
            const uint32_t o = out_base + (uint32_t)t_out * 262144u + (uint32_t)ph * 512u;
            *reinterpret_cast<float4*>(out + o)      = make_float4(f[0], f[1], f[2], f[3]);
            *reinterpret_cast<float4*>(out + o + 4u) = make_float4(f[4], f[5], f[6], f[7]);
        }
    }
}

extern "C" void kernel_launch(void* const* d_in, const int* in_sizes, int n_in,
                              void* d_out, int out_size, void* d_ws, size_t ws_size,
                              hipStream_t stream) {
    const float* in = (const float*)d_in[0];
    float* out = (float*)d_out;
    // total threads = 2*3*9*256*64 = 884736 = 3456 blocks * 256
    idwt_haar_kernel<<<dim3(3456), dim3(256), 0, stream>>>(in, out);
}